// Round 1
// baseline (621.941 us; speedup 1.0000x reference)
//
#include <hip/hip_runtime.h>

// upfirdn2d(x, k, up=2, down=1, pad=(2,1)) with separable k = outer([1,3,3,1])/16*4.
// Polyphase per axis (zeros outside range):
//   out[2a]   = 0.25*x[a-1] + 0.75*x[a]
//   out[2a+1] = 0.75*x[a]   + 0.25*x[a+1]
// x: [16,128,128,128] f32 -> out: [16,128,256,256] f32. Purely memory-bound.
//
// Structure: one wave per 32-input-row strip of one image (2048 imgs x 4 strips
// = 8192 waves = 32 waves/CU on 256 CUs: exact full residency, one dispatch).
// Rolling vertical window so each input row is loaded exactly once (float2/lane,
// 512B/wave contiguous); horizontal halo via 2 __shfl; each output row stored as
// one fully-contiguous 1KiB wave store (float4/lane, nontemporal: pure stream).
//
// Row pairing: iteration m emits rows (2m-1, 2m), both functions of h[m-1],h[m]:
//   row 2m-1 = 0.75*h[m-1] + 0.25*h[m]
//   row 2m   = 0.25*h[m-1] + 0.75*h[m]
// Strip s covers m in [32s, 32s+32); epilogue of last strip emits row 255 =
// 0.75*h[127] (h[128] = 0 from zero padding).

#define IH 128
#define IW 128
#define OH 256
#define OW 256
#define STRIPS 4
#define SROWS (IH / STRIPS)  // 32 input rows per wave

typedef __attribute__((ext_vector_type(4))) float f32x4;

__global__ __launch_bounds__(256) void upsample2x_kernel(
    const float* __restrict__ x, float* __restrict__ out) {
    const int lane = threadIdx.x & 63;
    const int wid  = threadIdx.x >> 6;
    const int gw   = blockIdx.x * 4 + wid;  // 0..8191
    const int img  = gw >> 2;               // 0..2047 (B*C)
    const int r0   = (gw & 3) * SROWS;
    const int r1   = r0 + SROWS;

    const float* __restrict__ xp = x + (size_t)img * (IH * IW);
    float* __restrict__ op       = out + (size_t)img * (OH * OW);

    const int c  = lane * 2;  // input cols c, c+1
    const int oc = lane * 4;  // output cols oc..oc+3

    // Horizontal polyphase filter for this lane's 4 output columns.
    // left = x[c-1] (prev lane's .y), right = x[c+2] (next lane's .x).
    auto hcalc = [&](float2 v, float* h) {
        float left  = __shfl_up(v.y, 1);
        float right = __shfl_down(v.x, 1);
        if (lane == 0)  left  = 0.f;   // col -1: zero pad
        if (lane == 63) right = 0.f;   // col 128: zero pad
        h[0] = 0.25f * left + 0.75f * v.x;
        h[1] = 0.75f * v.x  + 0.25f * v.y;
        h[2] = 0.25f * v.x  + 0.75f * v.y;
        h[3] = 0.75f * v.y  + 0.25f * right;
    };

    float hm1[4];  // h[m-1]
    if (r0 == 0) {
        hm1[0] = hm1[1] = hm1[2] = hm1[3] = 0.f;  // row -1: zero pad
    } else {
        float2 v = *(const float2*)(xp + (size_t)(r0 - 1) * IW + c);
        hcalc(v, hm1);
    }

    // Software pipeline: row m's data is loaded one iteration ahead.
    float2 vnext = *(const float2*)(xp + (size_t)r0 * IW + c);

#pragma unroll 4
    for (int m = r0; m < r1; ++m) {
        float2 vcur = vnext;
        int rn = (m + 1 < IH) ? (m + 1) : (IH - 1);  // clamp; value unused on last iter
        vnext = *(const float2*)(xp + (size_t)rn * IW + c);

        float hm[4];
        hcalc(vcur, hm);

        f32x4 o_odd, o_evn;
        o_odd.x = 0.75f * hm1[0] + 0.25f * hm[0];
        o_odd.y = 0.75f * hm1[1] + 0.25f * hm[1];
        o_odd.z = 0.75f * hm1[2] + 0.25f * hm[2];
        o_odd.w = 0.75f * hm1[3] + 0.25f * hm[3];
        o_evn.x = 0.25f * hm1[0] + 0.75f * hm[0];
        o_evn.y = 0.25f * hm1[1] + 0.75f * hm[1];
        o_evn.z = 0.25f * hm1[2] + 0.75f * hm[2];
        o_evn.w = 0.25f * hm1[3] + 0.75f * hm[3];

        if (m > 0)  // row -1 doesn't exist; wave-uniform branch
            __builtin_nontemporal_store(
                o_odd, (f32x4*)(op + (size_t)(2 * m - 1) * OW + oc));
        __builtin_nontemporal_store(
            o_evn, (f32x4*)(op + (size_t)(2 * m) * OW + oc));

        hm1[0] = hm[0]; hm1[1] = hm[1]; hm1[2] = hm[2]; hm1[3] = hm[3];
    }

    if (r1 == IH) {  // row 255 = 0.75*h[127] + 0.25*h[128], h[128] = 0
        f32x4 last;
        last.x = 0.75f * hm1[0];
        last.y = 0.75f * hm1[1];
        last.z = 0.75f * hm1[2];
        last.w = 0.75f * hm1[3];
        __builtin_nontemporal_store(
            last, (f32x4*)(op + (size_t)(OH - 1) * OW + oc));
    }
}

extern "C" void kernel_launch(void* const* d_in, const int* in_sizes, int n_in,
                              void* d_out, int out_size, void* d_ws, size_t ws_size,
                              hipStream_t stream) {
    const float* x = (const float*)d_in[0];
    // d_in[1] is the 4x4 FIR kernel: fixed separable [1,3,3,1] -> polyphase
    // weights 0.25/0.75 baked in above.
    float* out = (float*)d_out;

    const int waves = 2048 * STRIPS;       // imgs * strips = 8192
    const int block = 256;                 // 4 waves/block
    const int grid  = waves / 4;           // 2048 blocks = 8 blocks/CU, exact fill
    upsample2x_kernel<<<grid, block, 0, stream>>>(x, out);
}

// Round 2
// 608.414 us; speedup vs baseline: 1.0222x; 1.0222x over previous
//
#include <hip/hip_runtime.h>

// upfirdn2d(x, k, up=2, down=1, pad=(2,1)) with separable k = outer([1,3,3,1])/16*4.
// Polyphase per axis (zeros outside range):
//   out[2a]   = 0.25*x[a-1] + 0.75*x[a]
//   out[2a+1] = 0.75*x[a]   + 0.25*x[a+1]
// x: [16,128,128,128] f32 -> out: [16,128,256,256] f32. Purely memory-bound.
//
// Structure: one wave per 16-input-row strip of one image (2048 imgs x 8 strips
// = 16384 waves, 4096 blocks = 2x oversubscription for phase stagger + latency
// slack). Rolling vertical window: each input row loaded once per strip
// (float2/lane, 512B/wave contiguous); horizontal halo via 2 __shfl; each
// output row stored as one fully-contiguous 1KiB wave store.
// R2 change vs R1: plain stores (fillBuffer proves plain streaming stores hit
// 6.25 TB/s on this buffer; nt stores measured ~2.4 TB/s aggregate), STRIPS 4->8.
//
// Row pairing: iteration m emits rows (2m-1, 2m), both functions of h[m-1],h[m]:
//   row 2m-1 = 0.75*h[m-1] + 0.25*h[m]
//   row 2m   = 0.25*h[m-1] + 0.75*h[m]
// Strip covers m in [r0, r0+16); epilogue of last strip emits row 255 =
// 0.75*h[127] (h[128] = 0 from zero padding).

#define IH 128
#define IW 128
#define OH 256
#define OW 256
#define STRIPS 8
#define SROWS (IH / STRIPS)  // 16 input rows per wave

typedef __attribute__((ext_vector_type(4))) float f32x4;

__global__ __launch_bounds__(256) void upsample2x_kernel(
    const float* __restrict__ x, float* __restrict__ out) {
    const int lane = threadIdx.x & 63;
    const int wid  = threadIdx.x >> 6;
    const int gw   = blockIdx.x * 4 + wid;   // 0..16383
    const int img  = gw >> 3;                // 0..2047 (B*C)
    const int r0   = (gw & 7) * SROWS;
    const int r1   = r0 + SROWS;

    const float* __restrict__ xp = x + (size_t)img * (IH * IW);
    float* __restrict__ op       = out + (size_t)img * (OH * OW);

    const int c  = lane * 2;  // input cols c, c+1
    const int oc = lane * 4;  // output cols oc..oc+3

    // Horizontal polyphase filter for this lane's 4 output columns.
    // left = x[c-1] (prev lane's .y), right = x[c+2] (next lane's .x).
    auto hcalc = [&](float2 v, float* h) {
        float left  = __shfl_up(v.y, 1);
        float right = __shfl_down(v.x, 1);
        if (lane == 0)  left  = 0.f;   // col -1: zero pad
        if (lane == 63) right = 0.f;   // col 128: zero pad
        h[0] = 0.25f * left + 0.75f * v.x;
        h[1] = 0.75f * v.x  + 0.25f * v.y;
        h[2] = 0.25f * v.x  + 0.75f * v.y;
        h[3] = 0.75f * v.y  + 0.25f * right;
    };

    float hm1[4];  // h[m-1]
    if (r0 == 0) {
        hm1[0] = hm1[1] = hm1[2] = hm1[3] = 0.f;  // row -1: zero pad
    } else {
        float2 v = *(const float2*)(xp + (size_t)(r0 - 1) * IW + c);
        hcalc(v, hm1);
    }

    // Software pipeline: row m's data is loaded one iteration ahead.
    float2 vnext = *(const float2*)(xp + (size_t)r0 * IW + c);

#pragma unroll 4
    for (int m = r0; m < r1; ++m) {
        float2 vcur = vnext;
        int rn = (m + 1 < IH) ? (m + 1) : (IH - 1);  // clamp; value unused on last iter
        vnext = *(const float2*)(xp + (size_t)rn * IW + c);

        float hm[4];
        hcalc(vcur, hm);

        f32x4 o_odd, o_evn;
        o_odd.x = 0.75f * hm1[0] + 0.25f * hm[0];
        o_odd.y = 0.75f * hm1[1] + 0.25f * hm[1];
        o_odd.z = 0.75f * hm1[2] + 0.25f * hm[2];
        o_odd.w = 0.75f * hm1[3] + 0.25f * hm[3];
        o_evn.x = 0.25f * hm1[0] + 0.75f * hm[0];
        o_evn.y = 0.25f * hm1[1] + 0.75f * hm[1];
        o_evn.z = 0.25f * hm1[2] + 0.75f * hm[2];
        o_evn.w = 0.25f * hm1[3] + 0.75f * hm[3];

        if (m > 0)  // row -1 doesn't exist; wave-uniform branch
            *(f32x4*)(op + (size_t)(2 * m - 1) * OW + oc) = o_odd;
        *(f32x4*)(op + (size_t)(2 * m) * OW + oc) = o_evn;

        hm1[0] = hm[0]; hm1[1] = hm[1]; hm1[2] = hm[2]; hm1[3] = hm[3];
    }

    if (r1 == IH) {  // row 255 = 0.75*h[127] + 0.25*h[128], h[128] = 0
        f32x4 last;
        last.x = 0.75f * hm1[0];
        last.y = 0.75f * hm1[1];
        last.z = 0.75f * hm1[2];
        last.w = 0.75f * hm1[3];
        *(f32x4*)(op + (size_t)(OH - 1) * OW + oc) = last;
    }
}

extern "C" void kernel_launch(void* const* d_in, const int* in_sizes, int n_in,
                              void* d_out, int out_size, void* d_ws, size_t ws_size,
                              hipStream_t stream) {
    const float* x = (const float*)d_in[0];
    // d_in[1] is the 4x4 FIR kernel: fixed separable [1,3,3,1] -> polyphase
    // weights 0.25/0.75 baked in above.
    float* out = (float*)d_out;

    const int waves = 2048 * STRIPS;       // imgs * strips = 16384
    const int block = 256;                 // 4 waves/block
    const int grid  = waves / 4;           // 4096 blocks
    upsample2x_kernel<<<grid, block, 0, stream>>>(x, out);
}